// Round 14
// baseline (148.177 us; speedup 1.0000x reference)
//
#include <hip/hip_runtime.h>
#include <hip/hip_bf16.h>

// MultiScaleAttention: B=1,S=2048,D=1024,H=16,DH=64,WIN=128,DIL=4.
// ESTABLISHED: inputs fp32, output fp32, ws 256 MiB.
// Round-27: r26 (4-wave/32-q attn) failed absmax 0.18; two index-trace passes
// found nothing -> revert attn to r25 (145.4us known-good) rather than blind
// 3rd attempt. This round's single change: gemm0 BK 64->128 (KH=4 quad
// halves, 8 K-iters, 16 barrier events vs 32). m132's BK128 regression was
// occupancy-loss via 64KB LDS; here grid caps gemm0 at 3 blocks/CU anyway
// and LDS 24->48KB keeps 3/CU. gemm1 stays KH=2. attn/prep byte-identical
// to r25 (cvt_pk p-pack proven RNE, pair-processed quad-buffered K/V).

typedef __attribute__((ext_vector_type(8))) short s8v;   // 8 bf16
typedef __attribute__((ext_vector_type(4))) float f4v;   // 4 fp32

#define QSCALE 0.18033688011112042f   // 0.125 * log2(e)

__device__ __forceinline__ short f2bf(float f) {
  union { float f; unsigned u; } x; x.f = f;
  unsigned r = (x.u + 0x7FFF + ((x.u >> 16) & 1)) >> 16;   // RNE
  return (short)r;
}
__device__ __forceinline__ f4v mfma16(s8v a, s8v b, f4v c) {
  return __builtin_amdgcn_mfma_f32_16x16x32_bf16(a, b, c, 0, 0, 0);
}
__device__ __forceinline__ void load_lds16(const void* g, void* l) {
  __builtin_amdgcn_global_load_lds(
      (const __attribute__((address_space(1))) unsigned int*)g,
      (__attribute__((address_space(3))) unsigned int*)l, 16, 0, 0);
}
__device__ __forceinline__ float exp2f_fast(float x) {
  return __builtin_amdgcn_exp2f(x);     // v_exp_f32: D = 2^S0
}
__device__ __forceinline__ unsigned cvt_pk_bf16(float lo, float hi) {
  unsigned r;
  asm("v_cvt_pk_bf16_f32 %0, %1, %2" : "=v"(r) : "v"(lo), "v"(hi));
  return r;
}

__global__ __launch_bounds__(256)
void fill_const_kernel(float* __restrict__ out, int n, float v) {
  int i = blockIdx.x * 256 + threadIdx.x;
  if (i < n) out[i] = v;
}

// ---------- fused prep: transpose w_qkv (bx<48), transpose w_out (48-63),
// ---------- cast x->bf16 (bx>=64; 128 x-blocks x 16 y = 2048 cast chunks)
__global__ __launch_bounds__(256)
void prep_fused(const float* __restrict__ wq, short* __restrict__ wqT,
                const float* __restrict__ wo, short* __restrict__ woT,
                const float* __restrict__ x, short* __restrict__ xb) {
  const int bx = blockIdx.x, t = threadIdx.x;
  __shared__ float T[64][69];
  if (bx >= 64) {                      // cast region
    if (x) {
      int cb = (bx - 64) * 16 + blockIdx.y;
      int i = (cb * 256 + t) * 4;
      float4 v = *reinterpret_cast<const float4*>(&x[i]);
      union { short s[4]; int2 p; } u;
      u.s[0] = f2bf(v.x); u.s[1] = f2bf(v.y); u.s[2] = f2bf(v.z); u.s[3] = f2bf(v.w);
      *reinterpret_cast<int2*>(&xb[i]) = u.p;
    }
    return;
  }
  const float* src; short* dst; int N, bxx;
  if (bx < 48) { src = wq; dst = wqT; N = 3072; bxx = bx; }
  else         { src = wo; dst = woT; N = 1024; bxx = bx - 48; }
  const int K = 1024;
  const int n0 = bxx * 64, k0 = blockIdx.y * 64;
  for (int jb = t; jb < 1024; jb += 256) {
    int r = jb >> 4, c4 = (jb & 15) * 4;
    float4 v = *reinterpret_cast<const float4*>(&src[(size_t)(k0 + r) * N + n0 + c4]);
    T[c4 + 0][r] = v.x; T[c4 + 1][r] = v.y; T[c4 + 2][r] = v.z; T[c4 + 3][r] = v.w;
  }
  __syncthreads();
  for (int jb = t; jb < 512; jb += 256) {
    int n = jb >> 3, k8 = (jb & 7) * 8;
    union { short s[8]; int4 v; } p;
#pragma unroll
    for (int i = 0; i < 8; ++i) p.s[i] = f2bf(T[n][k8 + i]);
    *reinterpret_cast<int4*>(&dst[(size_t)(n0 + n) * K + k0 + k8]) = p.v;
  }
}

// ---------- vT/qb/kb epilogue helper ----------
// C/D layout col=lane&15, row=quad*4+reg. grow0 == 0 (mod 4).
__device__ __forceinline__ void g1_epilogue_store(
    int gcol, int grow0, const f4v& a,
    short* __restrict__ qb, short* __restrict__ kb, short* __restrict__ vT) {
  if (gcol >= 2048) {                  // vT, kappa-permuted layout
    int d = gcol - 2048;
    int j = grow0 >> 2;                // in-residue position; residue = r
    int gb = ((j >> 6) << 6) + (((j >> 5) & 1) << 5) +
             (((j >> 2) & 3) << 3) + (((j >> 4) & 1) << 2) + (j & 3);
    size_t base = (size_t)d * 2048 + gb;
#pragma unroll
    for (int r = 0; r < 4; ++r)
      vT[base + (r << 9)] = f2bf(a[r]);
  } else {
    short* dst = (gcol < 1024) ? qb : kb;
    float sc = (gcol < 1024) ? QSCALE : 1.0f;
    int c = gcol & 1023;
#pragma unroll
    for (int r = 0; r < 4; ++r)
      dst[(size_t)(grow0 + r) * 1024 + c] = f2bf(a[r] * sc);
  }
}

// ---------- MFMA GEMM, 64xNT tile, BK=32*KH as KH BK=32 halves ----------
// Per (32*KH)-K step: stage all KH halves (conflict-free 64B-row-stride
// layout each), ONE barrier pair, KHx(4xNTW) MFMA. NT in {64,128}, KH in {2,4}.
template <int COUT, bool AF32, int NT, int KH>
__global__ __launch_bounds__(256)
void gemm_tile(const void* __restrict__ Av, const short* __restrict__ Bt,
               short* __restrict__ qb, short* __restrict__ kb,
               short* __restrict__ vT, float* __restrict__ co,
               int K, int N) {
  __shared__ __align__(16) short As[KH][64 * 32];
  __shared__ __align__(16) short Bs[KH][NT * 32];
  const int tid = threadIdx.x, wave = tid >> 6;
  const int li = tid & 63;
  const int row0 = blockIdx.y * 64, col0 = blockIdx.x * NT;
  const int lr = li & 15, quad = li >> 4, lk = quad * 8;
  constexpr int NTW = NT / 64;          // n-16-tiles per wave (1 or 2)

  f4v acc[4][NTW];
#pragma unroll
  for (int i = 0; i < 4; ++i)
#pragma unroll
    for (int j = 0; j < NTW; ++j) acc[i][j] = (f4v){0.f, 0.f, 0.f, 0.f};

  for (int k0 = 0; k0 < K; k0 += 32 * KH) {
    __syncthreads();
#pragma unroll
    for (int kk = 0; kk < KH; ++kk) {
#pragma unroll
      for (int u = 0; u < NTW; ++u)
        load_lds16(Bt + (size_t)(col0 + u * 64 + (tid >> 2)) * K + k0 + kk * 32 + (tid & 3) * 8,
                   &Bs[kk][u * 2048 + wave * 512]);
      if (AF32) {
        const float* A = (const float*)Av;
#pragma unroll
        for (int c = 0; c < 2; ++c) {
          int j = c * 256 + tid;         // 512 float4 chunks per half
          int r = j >> 3, c4 = (j & 7) * 4;
          float4 v = *reinterpret_cast<const float4*>(
              &A[(size_t)(row0 + r) * K + k0 + kk * 32 + c4]);
          union { short s[4]; int2 v2; } p;
          p.s[0] = f2bf(v.x); p.s[1] = f2bf(v.y); p.s[2] = f2bf(v.z); p.s[3] = f2bf(v.w);
          *reinterpret_cast<int2*>(&As[kk][r * 32 + c4]) = p.v2;
        }
      } else {
        load_lds16((const short*)Av + (size_t)(row0 + (tid >> 2)) * K + k0 + kk * 32 + (tid & 3) * 8,
                   &As[kk][wave * 512]);
      }
    }
    __syncthreads();

#pragma unroll
    for (int kk = 0; kk < KH; ++kk) {
      s8v af[4], bfr[NTW];
#pragma unroll
      for (int mt = 0; mt < 4; ++mt)
        af[mt] = *reinterpret_cast<const s8v*>(&As[kk][(mt * 16 + lr) * 32 + lk]);
#pragma unroll
      for (int u = 0; u < NTW; ++u)
        bfr[u] = *reinterpret_cast<const s8v*>(&Bs[kk][(wave * (NT / 4) + u * 16 + lr) * 32 + lk]);
#pragma unroll
      for (int mt = 0; mt < 4; ++mt)
#pragma unroll
        for (int u = 0; u < NTW; ++u)
          acc[mt][u] = mfma16(af[mt], bfr[u], acc[mt][u]);
    }
  }

#pragma unroll
  for (int mt = 0; mt < 4; ++mt) {
#pragma unroll
    for (int u = 0; u < NTW; ++u) {
      int gcol = col0 + wave * (NT / 4) + u * 16 + lr;
      int grow0 = row0 + mt * 16 + quad * 4;
      if (COUT == 0) {
        g1_epilogue_store(gcol, grow0, acc[mt][u], qb, kb, vT);
      } else {
#pragma unroll
        for (int r = 0; r < 4; ++r)
          co[(size_t)(grow0 + r) * N + gcol] = acc[mt][u][r] * (1.0f / 3.0f);
      }
    }
  }
}

// ---------- unified flash attention: 8-wave key-split, register-P,
// ---------- PAIR-PROCESSED with quad-buffered K/V (one barrier / 2 tiles) ---
// (byte-identical to r25: cvt_pk p-pack, 145.4us verified)
__global__ __launch_bounds__(512, 2)
void attn_unified(const short* __restrict__ qb, const short* __restrict__ kb,
                  const short* __restrict__ vT, short* __restrict__ o) {
  __shared__ __align__(16) short Ks[4][64][72];
  __shared__ __align__(16) short Vt[4][64][72];   // [d][kappa]
  __shared__ float lX[2][4][16][4];               // [grp][wr][q][{lg,ll,ld}]

  const int tid = threadIdx.x;
  const int wave = tid >> 6, li = tid & 63;
  const int grp = wave >> 2, wr = wave & 3;
  const int b = blockIdx.x, h = b & 15, g = b >> 4;
  const int qcol = h * 64;
  const int lr = li & 15, quad = li >> 4, lk = quad * 8;
  const int wt2 = g >> 2;            // in-group tile holding the local window
  const int wH  = (g >> 1) & 1;      // which key-group holds the window
  const bool wgrp = (grp == wH);
  const int sr = tid >> 3, sc8 = (tid & 7) * 8;   // staging row / col

  s8v q0, q1;
  {
    const short* qrow = &qb[(size_t)(g * 64 + wr * 16 + lr) * 1024 + qcol];
    q0 = *reinterpret_cast<const s8v*>(&qrow[lk]);
    q1 = *reinterpret_cast<const s8v*>(&qrow[32 + lk]);
  }

  // stage tiles 0 and 1 into buffers 0 and 1 (rho=0, t8=0,1)
#pragma unroll
  for (int c = 0; c < 2; ++c) {
    int ks = (c * 64 + sr) << 2;
    *reinterpret_cast<int4*>(&Ks[c][sr][sc8]) =
        *reinterpret_cast<const int4*>(&kb[(size_t)ks * 1024 + qcol + sc8]);
    *reinterpret_cast<int4*>(&Vt[c][sr][sc8]) =
        *reinterpret_cast<const int4*>(&vT[(size_t)(h * 64 + sr) * 2048 + c * 64 + sc8]);
  }
  __syncthreads();

  float l_r = 0.f, l_loc = 0.f, l_dil = 0.f;
  f4v oacc[4], o_loc[4], o_dil[4];
#pragma unroll
  for (int i = 0; i < 4; ++i) {
    oacc[i]  = (f4v){0.f, 0.f, 0.f, 0.f};
    o_loc[i] = (f4v){0.f, 0.f, 0.f, 0.f};
    o_dil[i] = (f4v){0.f, 0.f, 0.f, 0.f};
  }

  const int koffA = ((grp * 2 + 0) * 16 + lr) * 72 + lk;
  const int koffB = ((grp * 2 + 1) * 16 + lr) * 72 + lk;
  const int voff  = lr * 72 + grp * 32 + lk;       // V frag base (nt=0)
  const short* KsF = &Ks[0][0][0];
  const short* VtF = &Vt[0][0][0];

#pragma unroll
  for (int rho = 0; rho < 4; ++rho) {
    const float sn0 = oacc[0][rho], sn1 = oacc[1][rho],
                sn2 = oacc[2][rho], sn3 = oacc[3][rho];
    const float lsn = l_r;

#pragma unroll 2
    for (int p8 = 0; p8 < 4; ++p8) {
      const int tA = rho * 8 + 2 * p8;
      const int bufA = (2 * p8) & 3;            // 0 or 2
      const int cbA = bufA * 4608, cbB = cbA + 4608;
      const bool pf = (tA < 30);
      const bool wtA = wgrp && (2 * p8 == wt2);
      const bool wtB = wgrp && (2 * p8 + 1 == wt2);

      // prefetch pair p+1 (tiles tA+2, tA+3) into registers
      int4 kpA, vpA, kpB, vpB;
      if (pf) {
        const int tnA = tA + 2, tnB = tA + 3;
        const int ksA = ((((tnA & 7) << 6) + sr) << 2) + (tnA >> 3);
        const int ksB = ((((tnB & 7) << 6) + sr) << 2) + (tnB >> 3);
        kpA = *reinterpret_cast<const int4*>(&kb[(size_t)ksA * 1024 + qcol + sc8]);
        vpA = *reinterpret_cast<const int4*>(
            &vT[(size_t)(h * 64 + sr) * 2048 + tnA * 64 + sc8]);
        kpB = *reinterpret_cast<const int4*>(&kb[(size_t)ksB * 1024 + qcol + sc8]);
        vpB = *reinterpret_cast<const int4*>(
            &vT[(size_t)(h * 64 + sr) * 2048 + tnB * 64 + sc8]);
      }

      // ---------------- tile A (buffer bufA) ----------------
      {
        f4v s4a = (f4v){0.f, 0.f, 0.f, 0.f};
        f4v s4b = (f4v){0.f, 0.f, 0.f, 0.f};
        s4a = mfma16(*reinterpret_cast<const s8v*>(&KsF[cbA + koffA]), q0, s4a);
        s4b = mfma16(*reinterpret_cast<const s8v*>(&KsF[cbA + koffB]), q0, s4b);
        s4a = mfma16(*reinterpret_cast<const s8v*>(&KsF[cbA + koffA + 32]), q1, s4a);
        s4b = mfma16(*reinterpret_cast<const s8v*>(&KsF[cbA + koffB + 32]), q1, s4b);

        float pa0 = exp2f_fast(s4a[0]), pa1 = exp2f_fast(s4a[1]),
              pa2 = exp2f_fast(s4a[2]), pa3 = exp2f_fast(s4a[3]);
        float pb0 = exp2f_fast(s4b[0]), pb1 = exp2f_fast(s4b[1]),
              pb2 = exp2f_fast(s4b[2]), pb3 = exp2f_fast(s4b[3]);
        float ps = ((pa0 + pa1) + (pa2 + pa3)) + ((pb0 + pb1) + (pb2 + pb3));
        union { unsigned u[4]; s8v v; } pk;
        pk.u[0] = cvt_pk_bf16(pa0, pa1);
        pk.u[1] = cvt_pk_bf16(pa2, pa3);
        pk.u[2] = cvt_pk_bf16(pb0, pb1);
        pk.u[3] = cvt_pk_bf16(pb2, pb3);
        l_r += ps;
        if (wtA) l_loc += ps;

        if (wtA) {
#pragma unroll
          for (int nt = 0; nt < 4; ++nt) {
            s8v bv = *reinterpret_cast<const s8v*>(&VtF[cbA + nt * 1152 + voff]);
            f4v dd = mfma16(pk.v, bv, (f4v){0.f, 0.f, 0.f, 0.f});
            oacc[nt] += dd;
            o_loc[nt] += dd;
          }
        } else {
#pragma unroll
          for (int nt = 0; nt < 4; ++nt) {
            s8v bv = *reinterpret_cast<const s8v*>(&VtF[cbA + nt * 1152 + voff]);
            oacc[nt] = mfma16(pk.v, bv, oacc[nt]);
          }
        }
      }

      // ---------------- tile B (buffer bufA+1) ----------------
      {
        f4v s4a = (f4v){0.f, 0.f, 0.f, 0.f};
        f4v s4b = (f4v){0.f, 0.f, 0.f, 0.f};
        s4a = mfma16(*reinterpret_cast<const s8v*>(&KsF[cbB + koffA]), q0, s4a);
        s4b = mfma16(*reinterpret_cast<const s8v*>(&KsF[cbB + koffB]), q0, s4b);
        s4a = mfma16(*reinterpret_cast<const s8v*>(&KsF[cbB + koffA + 32]), q1, s4a);
        s4b = mfma16(*reinterpret_cast<const s8v*>(&KsF[cbB + koffB + 32]), q1, s4b);

        float pa0 = exp2f_fast(s4a[0]), pa1 = exp2f_fast(s4a[1]),
              pa2 = exp2f_fast(s4a[2]), pa3 = exp2f_fast(s4a[3]);
        float pb0 = exp2f_fast(s4b[0]), pb1 = exp2f_fast(s4b[1]),
              pb2 = exp2f_fast(s4b[2]), pb3 = exp2f_fast(s4b[3]);
        float ps = ((pa0 + pa1) + (pa2 + pa3)) + ((pb0 + pb1) + (pb2 + pb3));
        union { unsigned u[4]; s8v v; } pk;
        pk.u[0] = cvt_pk_bf16(pa0, pa1);
        pk.u[1] = cvt_pk_bf16(pa2, pa3);
        pk.u[2] = cvt_pk_bf16(pb0, pb1);
        pk.u[3] = cvt_pk_bf16(pb2, pb3);
        l_r += ps;
        if (wtB) l_loc += ps;

        if (wtB) {
#pragma unroll
          for (int nt = 0; nt < 4; ++nt) {
            s8v bv = *reinterpret_cast<const s8v*>(&VtF[cbB + nt * 1152 + voff]);
            f4v dd = mfma16(pk.v, bv, (f4v){0.f, 0.f, 0.f, 0.f});
            oacc[nt] += dd;
            o_loc[nt] += dd;
          }
        } else {
#pragma unroll
          for (int nt = 0; nt < 4; ++nt) {
            s8v bv = *reinterpret_cast<const s8v*>(&VtF[cbB + nt * 1152 + voff]);
            oacc[nt] = mfma16(pk.v, bv, oacc[nt]);
          }
        }
      }

      // write prefetched pair into the OTHER buffer pair; one barrier
      if (pf) {
        const int wbA = bufA ^ 2;
        *reinterpret_cast<int4*>(&Ks[wbA][sr][sc8])     = kpA;
        *reinterpret_cast<int4*>(&Vt[wbA][sr][sc8])     = vpA;
        *reinterpret_cast<int4*>(&Ks[wbA + 1][sr][sc8]) = kpB;
        *reinterpret_cast<int4*>(&Vt[wbA + 1][sr][sc8]) = vpB;
      }
      __syncthreads();
    }

    // dilated delta: o-slot r==rho has q-residue rho; l lane-predicated
    if (((lr ^ rho) & 3) == 0) l_dil = l_r - lsn;
    o_dil[0][rho] = oacc[0][rho] - sn0;
    o_dil[1][rho] = oacc[1][rho] - sn1;
    o_dil[2][rho] = oacc[2][rho] - sn2;
    o_dil[3][rho] = oacc[3][rho] - sn3;
  }

  l_r   += __shfl_xor(l_r, 16);   l_r   += __shfl_xor(l_r, 32);
  l_loc += __shfl_xor(l_loc, 16); l_loc += __shfl_xor(l_loc, 32);
  l_dil += __shfl_xor(l_dil, 16); l_dil += __shfl_xor(l_dil, 32);
  if (li < 16) {
    lX[grp][wr][li][0] = l_r;
    lX[grp][wr][li][1] = l_loc;
    lX[grp][wr][li][2] = l_dil;
  }
  __syncthreads();

  f4v part[4];
#pragma unroll
  for (int r = 0; r < 4; ++r) {
    int q4 = quad * 4 + r;
    float lg = lX[0][wr][q4][0] + lX[1][wr][q4][0];
    float ll = lX[0][wr][q4][1] + lX[1][wr][q4][1];
    float ld = lX[0][wr][q4][2] + lX[1][wr][q4][2];
    float ig = 1.0f / lg, il = 1.0f / ll, id = 1.0f / ld;
#pragma unroll
    for (int nt = 0; nt < 4; ++nt)
      part[nt][r] = oacc[nt][r] * ig + o_loc[nt][r] * il + o_dil[nt][r] * id;
  }

  float* xch = reinterpret_cast<float*>(&Ks[0][0][0]);
  const int slot = wr * 64 + li;       // 0..255, stride-18 float rows
  if (grp == 1) {
#pragma unroll
    for (int nt = 0; nt < 4; ++nt)
#pragma unroll
      for (int hh = 0; hh < 2; ++hh) {
        float2 v2 = make_float2(part[nt][2 * hh], part[nt][2 * hh + 1]);
        *reinterpret_cast<float2*>(&xch[slot * 18 + (nt * 2 + hh) * 2]) = v2;
      }
  }
  __syncthreads();
  if (grp == 0) {
#pragma unroll
    for (int nt = 0; nt < 4; ++nt)
#pragma unroll
      for (int hh = 0; hh < 2; ++hh) {
        float2 v2 = *reinterpret_cast<const float2*>(&xch[slot * 18 + (nt * 2 + hh) * 2]);
        part[nt][2 * hh]     += v2.x;
        part[nt][2 * hh + 1] += v2.y;
      }
#pragma unroll
    for (int r = 0; r < 4; ++r) {
      int qs = g * 64 + wr * 16 + quad * 4 + r;
#pragma unroll
      for (int nt = 0; nt < 4; ++nt)
        o[(size_t)qs * 1024 + qcol + nt * 16 + lr] = f2bf(part[nt][r]);
    }
  }
}

extern "C" void kernel_launch(void* const* d_in, const int* in_sizes, int n_in,
                              void* d_out, int out_size, void* d_ws, size_t ws_size,
                              hipStream_t stream) {
  float* out = (float*)d_out;
  const int nfill = (out_size + 255) / 256;
  if (n_in != 3) { fill_const_kernel<<<nfill, 256, 0, stream>>>(out, out_size, 0.5f); return; }
  int ix = -1, iq = -1, io = -1;
  for (int i = 0; i < 3; ++i) {
    if      (in_sizes[i] == 2097152) ix = i;
    else if (in_sizes[i] == 3145728) iq = i;
    else if (in_sizes[i] == 1048576) io = i;
  }
  if (ix < 0 || iq < 0 || io < 0) { fill_const_kernel<<<nfill, 256, 0, stream>>>(out, out_size, 0.3f); return; }
  const float* x     = (const float*)d_in[ix];
  const float* w_qkv = (const float*)d_in[iq];
  const float* w_out = (const float*)d_in[io];

  char* ws = (char*)d_ws;
  const size_t MB = 1048576;
  const size_t needX = 24 * MB;
  const size_t needY = 20 * MB;

  if (ws_size >= needX) {
    short* qb     = (short*)(ws);                // 0..4 MB
    short* kb     = (short*)(ws + 4 * MB);       // 4..8
    short* vT     = (short*)(ws + 8 * MB);       // 8..12
    short* w_qkvT = (short*)(ws + 12 * MB);      // 12..18 (dead after gemm0)
    short* o      = (short*)(ws + 12 * MB);      // over dead w_qkvT
    short* w_outT = (short*)(ws + 18 * MB);      // 18..20 (no overlap)
    short* xb     = (short*)(ws + 20 * MB);      // 20..24
    prep_fused<<<dim3(192, 16), 256, 0, stream>>>(w_qkv, w_qkvT, w_out, w_outT, x, xb);
    gemm_tile<0, false, 128, 4><<<dim3(24, 32), 256, 0, stream>>>(xb, w_qkvT, qb, kb, vT, nullptr, 1024, 3072);
    attn_unified<<<512, 512, 0, stream>>>(qb, kb, vT, o);
    gemm_tile<1, false, 64, 2><<<dim3(16, 32), 256, 0, stream>>>(o, w_outT, nullptr, nullptr, nullptr, out, 1024, 1024);
  } else if (ws_size >= needY) {
    short* w_outT = (short*)(ws);                // 0..2
    short* qb     = (short*)(ws + 2 * MB);       // 2..6
    short* kb     = (short*)(ws + 6 * MB);       // 6..10
    short* vT     = (short*)(ws + 10 * MB);      // 10..14
    short* w_qkvT = (short*)(ws + 14 * MB);      // 14..20 (dead after gemm0)
    short* o      = (short*)(ws + 14 * MB);      // over dead w_qkvT
    prep_fused<<<dim3(64, 16), 256, 0, stream>>>(w_qkv, w_qkvT, w_out, w_outT, nullptr, nullptr);
    gemm_tile<0, true, 128, 4><<<dim3(24, 32), 256, 0, stream>>>(x, w_qkvT, qb, kb, vT, nullptr, 1024, 3072);
    attn_unified<<<512, 512, 0, stream>>>(qb, kb, vT, o);
    gemm_tile<1, false, 64, 2><<<dim3(16, 32), 256, 0, stream>>>(o, w_outT, nullptr, nullptr, nullptr, out, 1024, 1024);
  } else {
    fill_const_kernel<<<nfill, 256, 0, stream>>>(out, out_size, 0.2f);
  }
}

// Round 15
// 143.240 us; speedup vs baseline: 1.0345x; 1.0345x over previous
//
#include <hip/hip_runtime.h>
#include <hip/hip_bf16.h>

// MultiScaleAttention: B=1,S=2048,D=1024,H=16,DH=64,WIN=128,DIL=4.
// ESTABLISHED: inputs fp32, output fp32, ws 256 MiB.
// Round-28: async attn staging. r27 (KH=4 gemm0) mildly regressed -> gemm0
// back to KH=2 (r25 config). attn change: K/V staging via global_load_lds
// (width 16, linear dest = wave base + lane*16) instead of global->reg->
// ds_write. Pad dropped (72->64); bank conflicts on frag reads avoided by
// XOR-chunk swizzle applied BOTH sides: per-lane global source fetches
// logical chunk pc^(row&7) into physical chunk pc; frag reads use
// chunk^ (lr&7). Eliminates ~2MB/CU ds_write traffic (~6.8us LDS port),
// frees 32 prefetch VGPRs, LDS 77.8->67.6KB. Buffer-pair rotation and
// barrier placement identical to r25 (prev barrier guards overwrite;
// compiler vmcnt(0)-before-barrier guarantees completion).
// Numerics byte-identical to r25 (cvt_pk RNE p-pack etc).

typedef __attribute__((ext_vector_type(8))) short s8v;   // 8 bf16
typedef __attribute__((ext_vector_type(4))) float f4v;   // 4 fp32

#define QSCALE 0.18033688011112042f   // 0.125 * log2(e)

__device__ __forceinline__ short f2bf(float f) {
  union { float f; unsigned u; } x; x.f = f;
  unsigned r = (x.u + 0x7FFF + ((x.u >> 16) & 1)) >> 16;   // RNE
  return (short)r;
}
__device__ __forceinline__ f4v mfma16(s8v a, s8v b, f4v c) {
  return __builtin_amdgcn_mfma_f32_16x16x32_bf16(a, b, c, 0, 0, 0);
}
__device__ __forceinline__ void load_lds16(const void* g, void* l) {
  __builtin_amdgcn_global_load_lds(
      (const __attribute__((address_space(1))) unsigned int*)g,
      (__attribute__((address_space(3))) unsigned int*)l, 16, 0, 0);
}
__device__ __forceinline__ float exp2f_fast(float x) {
  return __builtin_amdgcn_exp2f(x);     // v_exp_f32: D = 2^S0
}
__device__ __forceinline__ unsigned cvt_pk_bf16(float lo, float hi) {
  unsigned r;
  asm("v_cvt_pk_bf16_f32 %0, %1, %2" : "=v"(r) : "v"(lo), "v"(hi));
  return r;
}

__global__ __launch_bounds__(256)
void fill_const_kernel(float* __restrict__ out, int n, float v) {
  int i = blockIdx.x * 256 + threadIdx.x;
  if (i < n) out[i] = v;
}

// ---------- fused prep: transpose w_qkv (bx<48), transpose w_out (48-63),
// ---------- cast x->bf16 (bx>=64; 128 x-blocks x 16 y = 2048 cast chunks)
__global__ __launch_bounds__(256)
void prep_fused(const float* __restrict__ wq, short* __restrict__ wqT,
                const float* __restrict__ wo, short* __restrict__ woT,
                const float* __restrict__ x, short* __restrict__ xb) {
  const int bx = blockIdx.x, t = threadIdx.x;
  __shared__ float T[64][69];
  if (bx >= 64) {                      // cast region
    if (x) {
      int cb = (bx - 64) * 16 + blockIdx.y;
      int i = (cb * 256 + t) * 4;
      float4 v = *reinterpret_cast<const float4*>(&x[i]);
      union { short s[4]; int2 p; } u;
      u.s[0] = f2bf(v.x); u.s[1] = f2bf(v.y); u.s[2] = f2bf(v.z); u.s[3] = f2bf(v.w);
      *reinterpret_cast<int2*>(&xb[i]) = u.p;
    }
    return;
  }
  const float* src; short* dst; int N, bxx;
  if (bx < 48) { src = wq; dst = wqT; N = 3072; bxx = bx; }
  else         { src = wo; dst = woT; N = 1024; bxx = bx - 48; }
  const int K = 1024;
  const int n0 = bxx * 64, k0 = blockIdx.y * 64;
  for (int jb = t; jb < 1024; jb += 256) {
    int r = jb >> 4, c4 = (jb & 15) * 4;
    float4 v = *reinterpret_cast<const float4*>(&src[(size_t)(k0 + r) * N + n0 + c4]);
    T[c4 + 0][r] = v.x; T[c4 + 1][r] = v.y; T[c4 + 2][r] = v.z; T[c4 + 3][r] = v.w;
  }
  __syncthreads();
  for (int jb = t; jb < 512; jb += 256) {
    int n = jb >> 3, k8 = (jb & 7) * 8;
    union { short s[8]; int4 v; } p;
#pragma unroll
    for (int i = 0; i < 8; ++i) p.s[i] = f2bf(T[n][k8 + i]);
    *reinterpret_cast<int4*>(&dst[(size_t)(n0 + n) * K + k0 + k8]) = p.v;
  }
}

// ---------- vT/qb/kb epilogue helper ----------
// C/D layout col=lane&15, row=quad*4+reg. grow0 == 0 (mod 4).
__device__ __forceinline__ void g1_epilogue_store(
    int gcol, int grow0, const f4v& a,
    short* __restrict__ qb, short* __restrict__ kb, short* __restrict__ vT) {
  if (gcol >= 2048) {                  // vT, kappa-permuted layout
    int d = gcol - 2048;
    int j = grow0 >> 2;                // in-residue position; residue = r
    int gb = ((j >> 6) << 6) + (((j >> 5) & 1) << 5) +
             (((j >> 2) & 3) << 3) + (((j >> 4) & 1) << 2) + (j & 3);
    size_t base = (size_t)d * 2048 + gb;
#pragma unroll
    for (int r = 0; r < 4; ++r)
      vT[base + (r << 9)] = f2bf(a[r]);
  } else {
    short* dst = (gcol < 1024) ? qb : kb;
    float sc = (gcol < 1024) ? QSCALE : 1.0f;
    int c = gcol & 1023;
#pragma unroll
    for (int r = 0; r < 4; ++r)
      dst[(size_t)(grow0 + r) * 1024 + c] = f2bf(a[r] * sc);
  }
}

// ---------- MFMA GEMM, 64xNT tile, BK=32*KH as KH BK=32 halves ----------
template <int COUT, bool AF32, int NT, int KH>
__global__ __launch_bounds__(256)
void gemm_tile(const void* __restrict__ Av, const short* __restrict__ Bt,
               short* __restrict__ qb, short* __restrict__ kb,
               short* __restrict__ vT, float* __restrict__ co,
               int K, int N) {
  __shared__ __align__(16) short As[KH][64 * 32];
  __shared__ __align__(16) short Bs[KH][NT * 32];
  const int tid = threadIdx.x, wave = tid >> 6;
  const int li = tid & 63;
  const int row0 = blockIdx.y * 64, col0 = blockIdx.x * NT;
  const int lr = li & 15, quad = li >> 4, lk = quad * 8;
  constexpr int NTW = NT / 64;          // n-16-tiles per wave (1 or 2)

  f4v acc[4][NTW];
#pragma unroll
  for (int i = 0; i < 4; ++i)
#pragma unroll
    for (int j = 0; j < NTW; ++j) acc[i][j] = (f4v){0.f, 0.f, 0.f, 0.f};

  for (int k0 = 0; k0 < K; k0 += 32 * KH) {
    __syncthreads();
#pragma unroll
    for (int kk = 0; kk < KH; ++kk) {
#pragma unroll
      for (int u = 0; u < NTW; ++u)
        load_lds16(Bt + (size_t)(col0 + u * 64 + (tid >> 2)) * K + k0 + kk * 32 + (tid & 3) * 8,
                   &Bs[kk][u * 2048 + wave * 512]);
      if (AF32) {
        const float* A = (const float*)Av;
#pragma unroll
        for (int c = 0; c < 2; ++c) {
          int j = c * 256 + tid;         // 512 float4 chunks per half
          int r = j >> 3, c4 = (j & 7) * 4;
          float4 v = *reinterpret_cast<const float4*>(
              &A[(size_t)(row0 + r) * K + k0 + kk * 32 + c4]);
          union { short s[4]; int2 v2; } p;
          p.s[0] = f2bf(v.x); p.s[1] = f2bf(v.y); p.s[2] = f2bf(v.z); p.s[3] = f2bf(v.w);
          *reinterpret_cast<int2*>(&As[kk][r * 32 + c4]) = p.v2;
        }
      } else {
        load_lds16((const short*)Av + (size_t)(row0 + (tid >> 2)) * K + k0 + kk * 32 + (tid & 3) * 8,
                   &As[kk][wave * 512]);
      }
    }
    __syncthreads();

#pragma unroll
    for (int kk = 0; kk < KH; ++kk) {
      s8v af[4], bfr[NTW];
#pragma unroll
      for (int mt = 0; mt < 4; ++mt)
        af[mt] = *reinterpret_cast<const s8v*>(&As[kk][(mt * 16 + lr) * 32 + lk]);
#pragma unroll
      for (int u = 0; u < NTW; ++u)
        bfr[u] = *reinterpret_cast<const s8v*>(&Bs[kk][(wave * (NT / 4) + u * 16 + lr) * 32 + lk]);
#pragma unroll
      for (int mt = 0; mt < 4; ++mt)
#pragma unroll
        for (int u = 0; u < NTW; ++u)
          acc[mt][u] = mfma16(af[mt], bfr[u], acc[mt][u]);
    }
  }

#pragma unroll
  for (int mt = 0; mt < 4; ++mt) {
#pragma unroll
    for (int u = 0; u < NTW; ++u) {
      int gcol = col0 + wave * (NT / 4) + u * 16 + lr;
      int grow0 = row0 + mt * 16 + quad * 4;
      if (COUT == 0) {
        g1_epilogue_store(gcol, grow0, acc[mt][u], qb, kb, vT);
      } else {
#pragma unroll
        for (int r = 0; r < 4; ++r)
          co[(size_t)(grow0 + r) * N + gcol] = acc[mt][u][r] * (1.0f / 3.0f);
      }
    }
  }
}

// ---------- unified flash attention: 8-wave key-split, register-P,
// ---------- pair-processed quad-buffered K/V staged via global_load_lds ----
// 512 blocks (h=b&15, g=b>>4), 512 threads = 8 waves.
// LDS buffers are UNPADDED [64][64] shorts; gload_lds dest = wave base +
// lane*16 (linear). Physical chunk pc of row holds LOGICAL chunk
// pc ^ (row&7) (per-lane source pre-swizzle); frag reads use chunk ^ (lr&7).
// Tiles residue-major, tile t -> buf t&3; pair p computes 2p,2p+1, issues
// async loads for 2p+2,2p+3 into the other buffer pair, ONE barrier/pair.
__global__ __launch_bounds__(512, 2)
void attn_unified(const short* __restrict__ qb, const short* __restrict__ kb,
                  const short* __restrict__ vT, short* __restrict__ o) {
  __shared__ __align__(16) short Ks[4][64][64];
  __shared__ __align__(16) short Vt[4][64][64];   // [d][kappa]
  __shared__ float lX[2][4][16][4];               // [grp][wr][q][{lg,ll,ld}]

  const int tid = threadIdx.x;
  const int wave = tid >> 6, li = tid & 63;
  const int grp = wave >> 2, wr = wave & 3;
  const int b = blockIdx.x, h = b & 15, g = b >> 4;
  const int qcol = h * 64;
  const int lr = li & 15, quad = li >> 4, lk = quad * 8;
  const int wt2 = g >> 2;            // in-group tile holding the local window
  const int wH  = (g >> 1) & 1;      // which key-group holds the window
  const bool wgrp = (grp == wH);

  // staging geometry: thread covers dest chunk tid -> row=tid>>3, pc=tid&7;
  // fetches logical chunk sq8 = pc ^ (row&7) from global.
  const int srow = tid >> 3, spc = tid & 7;
  const int sq8 = spc ^ (srow & 7);
  short* KsB = &Ks[0][0][0];
  short* VtB = &Vt[0][0][0];
  short* ldsKW = KsB + wave * 512;   // wave-uniform dest base (buf 0)
  short* ldsVW = VtB + wave * 512;

  s8v q0, q1;
  {
    const short* qrow = &qb[(size_t)(g * 64 + wr * 16 + lr) * 1024 + qcol];
    q0 = *reinterpret_cast<const s8v*>(&qrow[lk]);
    q1 = *reinterpret_cast<const s8v*>(&qrow[32 + lk]);
  }

  // stage tiles 0 and 1 into buffers 0 and 1 (rho=0, t8=0,1)
#pragma unroll
  for (int c = 0; c < 2; ++c) {
    const int ksr = (c * 64 + srow) << 2;           // t=c: t&7=c, t>>3=0
    load_lds16(&kb[(size_t)ksr * 1024 + qcol + sq8 * 8], ldsKW + c * 4096);
    load_lds16(&vT[(size_t)(h * 64 + srow) * 2048 + c * 64 + sq8 * 8],
               ldsVW + c * 4096);
  }
  __syncthreads();

  float l_r = 0.f, l_loc = 0.f, l_dil = 0.f;
  f4v oacc[4], o_loc[4], o_dil[4];
#pragma unroll
  for (int i = 0; i < 4; ++i) {
    oacc[i]  = (f4v){0.f, 0.f, 0.f, 0.f};
    o_loc[i] = (f4v){0.f, 0.f, 0.f, 0.f};
    o_dil[i] = (f4v){0.f, 0.f, 0.f, 0.f};
  }

  // frag-read offsets (shorts): XOR-deswizzle with xa = lr&7
  const int xa = lr & 7;
  const int rowA = (grp * 32 + lr) * 64, rowB = rowA + 16 * 64;
  const int kco0 = ((quad ^ xa) << 3);              // d 0..31 chunk
  const int kco1 = (((4 + quad) ^ xa) << 3);        // d 32..63 chunk
  const int vco  = ((((grp << 2) + quad) ^ xa) << 3);
  const short* KsF = KsB;
  const short* VtF = VtB;

#pragma unroll
  for (int rho = 0; rho < 4; ++rho) {
    const float sn0 = oacc[0][rho], sn1 = oacc[1][rho],
                sn2 = oacc[2][rho], sn3 = oacc[3][rho];
    const float lsn = l_r;

#pragma unroll 2
    for (int p8 = 0; p8 < 4; ++p8) {
      const int tA = rho * 8 + 2 * p8;
      const int bufA = (2 * p8) & 3;            // 0 or 2
      const int cbA = bufA * 4096, cbB = cbA + 4096;
      const bool pf = (tA < 30);
      const bool wtA = wgrp && (2 * p8 == wt2);
      const bool wtB = wgrp && (2 * p8 + 1 == wt2);

      // issue async loads for pair p+1 (tiles tA+2, tA+3) into other bufs
      if (pf) {
        const int wb = bufA ^ 2;
        const int tnA = tA + 2, tnB = tA + 3;
        const int krA = ((((tnA & 7) << 6) + srow) << 2) + (tnA >> 3);
        const int krB = ((((tnB & 7) << 6) + srow) << 2) + (tnB >> 3);
        load_lds16(&kb[(size_t)krA * 1024 + qcol + sq8 * 8], ldsKW + wb * 4096);
        load_lds16(&vT[(size_t)(h * 64 + srow) * 2048 + tnA * 64 + sq8 * 8],
                   ldsVW + wb * 4096);
        load_lds16(&kb[(size_t)krB * 1024 + qcol + sq8 * 8],
                   ldsKW + (wb + 1) * 4096);
        load_lds16(&vT[(size_t)(h * 64 + srow) * 2048 + tnB * 64 + sq8 * 8],
                   ldsVW + (wb + 1) * 4096);
      }

      // ---------------- tile A (buffer bufA) ----------------
      {
        f4v s4a = (f4v){0.f, 0.f, 0.f, 0.f};
        f4v s4b = (f4v){0.f, 0.f, 0.f, 0.f};
        s4a = mfma16(*reinterpret_cast<const s8v*>(&KsF[cbA + rowA + kco0]), q0, s4a);
        s4b = mfma16(*reinterpret_cast<const s8v*>(&KsF[cbA + rowB + kco0]), q0, s4b);
        s4a = mfma16(*reinterpret_cast<const s8v*>(&KsF[cbA + rowA + kco1]), q1, s4a);
        s4b = mfma16(*reinterpret_cast<const s8v*>(&KsF[cbA + rowB + kco1]), q1, s4b);

        float pa0 = exp2f_fast(s4a[0]), pa1 = exp2f_fast(s4a[1]),
              pa2 = exp2f_fast(s4a[2]), pa3 = exp2f_fast(s4a[3]);
        float pb0 = exp2f_fast(s4b[0]), pb1 = exp2f_fast(s4b[1]),
              pb2 = exp2f_fast(s4b[2]), pb3 = exp2f_fast(s4b[3]);
        float ps = ((pa0 + pa1) + (pa2 + pa3)) + ((pb0 + pb1) + (pb2 + pb3));
        union { unsigned u[4]; s8v v; } pk;
        pk.u[0] = cvt_pk_bf16(pa0, pa1);
        pk.u[1] = cvt_pk_bf16(pa2, pa3);
        pk.u[2] = cvt_pk_bf16(pb0, pb1);
        pk.u[3] = cvt_pk_bf16(pb2, pb3);
        l_r += ps;
        if (wtA) l_loc += ps;

        if (wtA) {
#pragma unroll
          for (int nt = 0; nt < 4; ++nt) {
            s8v bv = *reinterpret_cast<const s8v*>(
                &VtF[cbA + (nt * 16 + lr) * 64 + vco]);
            f4v dd = mfma16(pk.v, bv, (f4v){0.f, 0.f, 0.f, 0.f});
            oacc[nt] += dd;
            o_loc[nt] += dd;
          }
        } else {
#pragma unroll
          for (int nt = 0; nt < 4; ++nt) {
            s8v bv = *reinterpret_cast<const s8v*>(
                &VtF[cbA + (nt * 16 + lr) * 64 + vco]);
            oacc[nt] = mfma16(pk.v, bv, oacc[nt]);
          }
        }
      }

      // ---------------- tile B (buffer bufA+1) ----------------
      {
        f4v s4a = (f4v){0.f, 0.f, 0.f, 0.f};
        f4v s4b = (f4v){0.f, 0.f, 0.f, 0.f};
        s4a = mfma16(*reinterpret_cast<const s8v*>(&KsF[cbB + rowA + kco0]), q0, s4a);
        s4b = mfma16(*reinterpret_cast<const s8v*>(&KsF[cbB + rowB + kco0]), q0, s4b);
        s4a = mfma16(*reinterpret_cast<const s8v*>(&KsF[cbB + rowA + kco1]), q1, s4a);
        s4b = mfma16(*reinterpret_cast<const s8v*>(&KsF[cbB + rowB + kco1]), q1, s4b);

        float pa0 = exp2f_fast(s4a[0]), pa1 = exp2f_fast(s4a[1]),
              pa2 = exp2f_fast(s4a[2]), pa3 = exp2f_fast(s4a[3]);
        float pb0 = exp2f_fast(s4b[0]), pb1 = exp2f_fast(s4b[1]),
              pb2 = exp2f_fast(s4b[2]), pb3 = exp2f_fast(s4b[3]);
        float ps = ((pa0 + pa1) + (pa2 + pa3)) + ((pb0 + pb1) + (pb2 + pb3));
        union { unsigned u[4]; s8v v; } pk;
        pk.u[0] = cvt_pk_bf16(pa0, pa1);
        pk.u[1] = cvt_pk_bf16(pa2, pa3);
        pk.u[2] = cvt_pk_bf16(pb0, pb1);
        pk.u[3] = cvt_pk_bf16(pb2, pb3);
        l_r += ps;
        if (wtB) l_loc += ps;

        if (wtB) {
#pragma unroll
          for (int nt = 0; nt < 4; ++nt) {
            s8v bv = *reinterpret_cast<const s8v*>(
                &VtF[cbB + (nt * 16 + lr) * 64 + vco]);
            f4v dd = mfma16(pk.v, bv, (f4v){0.f, 0.f, 0.f, 0.f});
            oacc[nt] += dd;
            o_loc[nt] += dd;
          }
        } else {
#pragma unroll
          for (int nt = 0; nt < 4; ++nt) {
            s8v bv = *reinterpret_cast<const s8v*>(
                &VtF[cbB + (nt * 16 + lr) * 64 + vco]);
            oacc[nt] = mfma16(pk.v, bv, oacc[nt]);
          }
        }
      }

      // one barrier per pair: drains the async loads (compiler emits
      // s_waitcnt vmcnt(0) before s_barrier) and releases the other bufs
      __syncthreads();
    }

    // dilated delta: o-slot r==rho has q-residue rho; l lane-predicated
    if (((lr ^ rho) & 3) == 0) l_dil = l_r - lsn;
    o_dil[0][rho] = oacc[0][rho] - sn0;
    o_dil[1][rho] = oacc[1][rho] - sn1;
    o_dil[2][rho] = oacc[2][rho] - sn2;
    o_dil[3][rho] = oacc[3][rho] - sn3;
  }

  l_r   += __shfl_xor(l_r, 16);   l_r   += __shfl_xor(l_r, 32);
  l_loc += __shfl_xor(l_loc, 16); l_loc += __shfl_xor(l_loc, 32);
  l_dil += __shfl_xor(l_dil, 16); l_dil += __shfl_xor(l_dil, 32);
  if (li < 16) {
    lX[grp][wr][li][0] = l_r;
    lX[grp][wr][li][1] = l_loc;
    lX[grp][wr][li][2] = l_dil;
  }
  __syncthreads();

  f4v part[4];
#pragma unroll
  for (int r = 0; r < 4; ++r) {
    int q4 = quad * 4 + r;
    float lg = lX[0][wr][q4][0] + lX[1][wr][q4][0];
    float ll = lX[0][wr][q4][1] + lX[1][wr][q4][1];
    float ld = lX[0][wr][q4][2] + lX[1][wr][q4][2];
    float ig = 1.0f / lg, il = 1.0f / ll, id = 1.0f / ld;
#pragma unroll
    for (int nt = 0; nt < 4; ++nt)
      part[nt][r] = oacc[nt][r] * ig + o_loc[nt][r] * il + o_dil[nt][r] * id;
  }

  float* xch = reinterpret_cast<float*>(&Ks[0][0][0]);
  const int slot = wr * 64 + li;       // 0..255, stride-18 float rows
  if (grp == 1) {
#pragma unroll
    for (int nt = 0; nt < 4; ++nt)
#pragma unroll
      for (int hh = 0; hh < 2; ++hh) {
        float2 v2 = make_float2(part[nt][2 * hh], part[nt][2 * hh + 1]);
        *reinterpret_cast<float2*>(&xch[slot * 18 + (nt * 2 + hh) * 2]) = v2;
      }
  }
  __syncthreads();
  if (grp == 0) {
#pragma unroll
    for (int nt = 0; nt < 4; ++nt)
#pragma unroll
      for (int hh = 0; hh < 2; ++hh) {
        float2 v2 = *reinterpret_cast<const float2*>(&xch[slot * 18 + (nt * 2 + hh) * 2]);
        part[nt][2 * hh]     += v2.x;
        part[nt][2 * hh + 1] += v2.y;
      }
#pragma unroll
    for (int r = 0; r < 4; ++r) {
      int qs = g * 64 + wr * 16 + quad * 4 + r;
#pragma unroll
      for (int nt = 0; nt < 4; ++nt)
        o[(size_t)qs * 1024 + qcol + nt * 16 + lr] = f2bf(part[nt][r]);
    }
  }
}

extern "C" void kernel_launch(void* const* d_in, const int* in_sizes, int n_in,
                              void* d_out, int out_size, void* d_ws, size_t ws_size,
                              hipStream_t stream) {
  float* out = (float*)d_out;
  const int nfill = (out_size + 255) / 256;
  if (n_in != 3) { fill_const_kernel<<<nfill, 256, 0, stream>>>(out, out_size, 0.5f); return; }
  int ix = -1, iq = -1, io = -1;
  for (int i = 0; i < 3; ++i) {
    if      (in_sizes[i] == 2097152) ix = i;
    else if (in_sizes[i] == 3145728) iq = i;
    else if (in_sizes[i] == 1048576) io = i;
  }
  if (ix < 0 || iq < 0 || io < 0) { fill_const_kernel<<<nfill, 256, 0, stream>>>(out, out_size, 0.3f); return; }
  const float* x     = (const float*)d_in[ix];
  const float* w_qkv = (const float*)d_in[iq];
  const float* w_out = (const float*)d_in[io];

  char* ws = (char*)d_ws;
  const size_t MB = 1048576;
  const size_t needX = 24 * MB;
  const size_t needY = 20 * MB;

  if (ws_size >= needX) {
    short* qb     = (short*)(ws);                // 0..4 MB
    short* kb     = (short*)(ws + 4 * MB);       // 4..8
    short* vT     = (short*)(ws + 8 * MB);       // 8..12
    short* w_qkvT = (short*)(ws + 12 * MB);      // 12..18 (dead after gemm0)
    short* o      = (short*)(ws + 12 * MB);      // over dead w_qkvT
    short* w_outT = (short*)(ws + 18 * MB);      // 18..20 (no overlap)
    short* xb     = (short*)(ws + 20 * MB);      // 20..24
    prep_fused<<<dim3(192, 16), 256, 0, stream>>>(w_qkv, w_qkvT, w_out, w_outT, x, xb);
    gemm_tile<0, false, 128, 2><<<dim3(24, 32), 256, 0, stream>>>(xb, w_qkvT, qb, kb, vT, nullptr, 1024, 3072);
    attn_unified<<<512, 512, 0, stream>>>(qb, kb, vT, o);
    gemm_tile<1, false, 64, 2><<<dim3(16, 32), 256, 0, stream>>>(o, w_outT, nullptr, nullptr, nullptr, out, 1024, 1024);
  } else if (ws_size >= needY) {
    short* w_outT = (short*)(ws);                // 0..2
    short* qb     = (short*)(ws + 2 * MB);       // 2..6
    short* kb     = (short*)(ws + 6 * MB);       // 6..10
    short* vT     = (short*)(ws + 10 * MB);      // 10..14
    short* w_qkvT = (short*)(ws + 14 * MB);      // 14..20 (dead after gemm0)
    short* o      = (short*)(ws + 14 * MB);      // over dead w_qkvT
    prep_fused<<<dim3(64, 16), 256, 0, stream>>>(w_qkv, w_qkvT, w_out, w_outT, nullptr, nullptr);
    gemm_tile<0, true, 128, 2><<<dim3(24, 32), 256, 0, stream>>>(x, w_qkvT, qb, kb, vT, nullptr, 1024, 3072);
    attn_unified<<<512, 512, 0, stream>>>(qb, kb, vT, o);
    gemm_tile<1, false, 64, 2><<<dim3(16, 32), 256, 0, stream>>>(o, w_outT, nullptr, nullptr, nullptr, out, 1024, 1024);
  } else {
    fill_const_kernel<<<nfill, 256, 0, stream>>>(out, out_size, 0.2f);
  }
}